// Round 4
// baseline (2583.801 us; speedup 1.0000x reference)
//
#include <hip/hip_runtime.h>
#include <cstddef>

// FlowNetC correlation: B=8, C=256, H=96, W=128, D=21 (disp stride 2, max 20)
// out[b, iy*21+ix, y, x] = (1/C) * sum_c in1[b,c,y,x] * in2[b,c,y+2*(iy-10),x+2*(ix-10)]
//
// Block = (b, 16-row y-tile, iy), all 21 ix. Parity-split in2 in LDS,
// double-buffered, ONE raw s_barrier per 2-channel chunk (lgkmcnt-only wait:
// the in2 register prefetch stays in flight across the barrier under the
// whole compute phase — counted vmcnt discipline, T3/T4 minimum form).
// in1 via coalesced float4 + DPP lane^1 exchange (VALU pipe). acc[8][21].

#define CC 256
#define HH 96
#define WW 128
#define DD 21
#define TY 16
#define CK 2
#define NCHUNK (CC / CK)        // 128
#define HWi (HH * WW)           // 12288
#define CHW (CK * HH * WW)      // 24576

#define S2 92                   // plane stride: 10 pad + 64 data + 18 pad
#define S2_TOT (CK * TY * 2 * S2)   // 5888 floats = 23.5 KB per buffer

__device__ __forceinline__ float4 dppswap4(float4 x) {
    float4 y;
    y.x = __int_as_float(__builtin_amdgcn_mov_dpp(__float_as_int(x.x), 0xB1, 0xF, 0xF, true));
    y.y = __int_as_float(__builtin_amdgcn_mov_dpp(__float_as_int(x.y), 0xB1, 0xF, 0xF, true));
    y.z = __int_as_float(__builtin_amdgcn_mov_dpp(__float_as_int(x.z), 0xB1, 0xF, 0xF, true));
    y.w = __int_as_float(__builtin_amdgcn_mov_dpp(__float_as_int(x.w), 0xB1, 0xF, 0xF, true));
    return y;
}

// Barrier WITHOUT the vmcnt drain __syncthreads() would emit: ds_writes must
// be visible (lgkmcnt(0)), but global loads may stay outstanding.
__device__ __forceinline__ void lds_barrier() {
    asm volatile("s_waitcnt lgkmcnt(0)" ::: "memory");
    __builtin_amdgcn_s_barrier();
}

__global__ __launch_bounds__(256, 2) void corr_kernel(const float* __restrict__ in1,
                                                      const float* __restrict__ in2,
                                                      float* __restrict__ out)
{
    __shared__ __align__(16) float s2[2][S2_TOT];

    // 1008 blocks = 8 XCDs * 126; all 21 iy of a (b,y-tile) on one XCD's L2.
    const int bx = blockIdx.x;
    const int logical = (bx & 7) * 126 + (bx >> 3);
    const int iy = logical % DD;
    const int t  = logical / DD;
    const int y0 = (t % 6) * TY;
    const int b  = t / 6;

    // lane map: tid = r*16 + g*2 + p  (p = x-parity, g = 8-pixel group, r = row)
    const int tid = threadIdx.x;
    const int p = tid & 1;
    const int g = (tid >> 1) & 7;
    const int r = tid >> 4;
    const int u0 = g * 8;               // first half-position (8 per thread)

    // pre-zero BOTH buffers: x-pads and OOB rows stay zero forever
    for (int i = tid; i < 2 * S2_TOT; i += 256) ((float*)s2)[i] = 0.0f;

    const float* base1 = in1 + (size_t)b * CC * HWi;
    const float* base2 = in2 + (size_t)b * CC * HWi;

    // in2 staging map: 4 float4 loads/thread/chunk
    int o2b[4], l2a[4];
    bool ok2[4];
#pragma unroll
    for (int i = 0; i < 4; ++i) {
        const int v   = i * 256 + tid;
        const int ck  = v >> 9;
        const int rem = v & 511;
        const int row = rem >> 5;
        const int xq  = rem & 31;
        const int y2  = y0 + row + 2 * iy - 20;
        ok2[i] = ((unsigned)y2 < (unsigned)HH);
        o2b[i] = (ck * HH + (ok2[i] ? y2 : 0)) * WW + xq * 4;
        l2a[i] = ((ck * TY + row) * 2) * S2 + 10 + xq * 2;   // even plane; odd = +S2
    }

    // in1: thread's 2 float4 cover x in [16g+8p, 16g+8p+8)
    const int a_off0 = (y0 + r) * WW + 16 * g + 8 * p;

    float acc[8][DD];
#pragma unroll
    for (int pi = 0; pi < 8; ++pi)
#pragma unroll
        for (int k = 0; k < DD; ++k) acc[pi][k] = 0.0f;

    __syncthreads();   // one full drain: LDS zeroing visible to all

    // prologue: chunk-0 in2 loads
    float4 r2[4];
#pragma unroll
    for (int i = 0; i < 4; ++i) r2[i] = *(const float4*)(base2 + o2b[i]);

    int m = 0;

#define CHUNK_BODY(BUF)                                                        \
    {                                                                          \
        float* sb = &s2[(BUF)][0];                                             \
        /* ds_write waits (counted) only on this chunk's prefetched r2 */      \
        _Pragma("unroll")                                                      \
        for (int i = 0; i < 4; ++i) {                                          \
            if (ok2[i]) {                                                      \
                *(float2*)&sb[l2a[i]]      = make_float2(r2[i].x, r2[i].z);    \
                *(float2*)&sb[l2a[i] + S2] = make_float2(r2[i].y, r2[i].w);    \
            }                                                                  \
        }                                                                      \
        /* in1 loads for chunk m FIRST (a-use waits vmcnt(4), not 0) */        \
        const float* ap = base1 + (size_t)m * CHW + a_off0;                    \
        const float4 ma0 = *(const float4*)(ap);                               \
        const float4 mb0 = *(const float4*)(ap + 4);                           \
        const float4 ma1 = *(const float4*)(ap + HWi);                         \
        const float4 mb1 = *(const float4*)(ap + HWi + 4);                     \
        /* in2 prefetch chunk m+1: stays in flight across the raw barrier */   \
        {                                                                      \
            const int nm = (m + 1) & (NCHUNK - 1);                             \
            const float* bp = base2 + (size_t)nm * CHW;                        \
            _Pragma("unroll")                                                  \
            for (int i = 0; i < 4; ++i)                                        \
                r2[i] = *(const float4*)(bp + o2b[i]);                         \
        }                                                                      \
        lds_barrier();                                                         \
        _Pragma("unroll")                                                      \
        for (int ck = 0; ck < CK; ++ck) {                                      \
            const float* pl = &sb[((ck * TY + r) * 2 + p) * S2 + u0];          \
            float v[28];                                                       \
            _Pragma("unroll")                                                  \
            for (int j = 0; j < 7; ++j) {                                      \
                const float4 t4 = *(const float4*)(pl + 4 * j);                \
                v[4*j+0] = t4.x; v[4*j+1] = t4.y;                              \
                v[4*j+2] = t4.z; v[4*j+3] = t4.w;                              \
            }                                                                  \
            const float4 ma = ck ? ma1 : ma0;                                  \
            const float4 mb = ck ? mb1 : mb0;                                  \
            const float4 qa = dppswap4(ma);                                    \
            const float4 qb = dppswap4(mb);                                    \
            float a[8];                                                        \
            a[0] = p ? qa.y : ma.x;  a[1] = p ? qa.w : ma.z;                   \
            a[2] = p ? qb.y : mb.x;  a[3] = p ? qb.w : mb.z;                   \
            a[4] = p ? ma.y : qa.x;  a[5] = p ? ma.w : qa.z;                   \
            a[6] = p ? mb.y : qb.x;  a[7] = p ? mb.w : qb.z;                   \
            _Pragma("unroll")                                                  \
            for (int pi = 0; pi < 8; ++pi)                                     \
                _Pragma("unroll")                                              \
                for (int k = 0; k < DD; ++k)                                   \
                    acc[pi][k] = fmaf(a[pi], v[pi + k], acc[pi][k]);           \
        }                                                                      \
        ++m;                                                                   \
    }

#pragma unroll 1
    for (int mm = 0; mm < NCHUNK / 2; ++mm) {
        CHUNK_BODY(0)
        CHUNK_BODY(1)
    }
#undef CHUNK_BODY

    // epilogue: scale + store (L2 write-combines the stride-2 pattern)
    const float sc = 1.0f / (float)CC;
    const size_t hw = (size_t)HWi;
    size_t ob = ((size_t)b * (DD * DD) + (size_t)(iy * DD)) * hw
              + (size_t)(y0 + r) * WW + 16 * g + p;
#pragma unroll
    for (int k = 0; k < DD; ++k) {
#pragma unroll
        for (int pi = 0; pi < 8; ++pi)
            out[ob + 2 * pi] = acc[pi][k] * sc;
        ob += hw;
    }
}

extern "C" void kernel_launch(void* const* d_in, const int* in_sizes, int n_in,
                              void* d_out, int out_size, void* d_ws, size_t ws_size,
                              hipStream_t stream)
{
    const float* in1 = (const float*)d_in[0];
    const float* in2 = (const float*)d_in[1];
    float* out = (float*)d_out;
    (void)in_sizes; (void)n_in; (void)d_ws; (void)ws_size; (void)out_size;

    corr_kernel<<<dim3(8 * 6 * DD), dim3(256), 0, stream>>>(in1, in2, out);
}

// Round 7
// 718.269 us; speedup vs baseline: 3.5973x; 3.5973x over previous
//
#include <hip/hip_runtime.h>
#include <cstddef>

// FlowNetC correlation: B=8, C=256, H=96, W=128, D=21 (disp stride 2, max 20)
// out[b, iy*21+ix, y, x] = (1/C) * sum_c in1[b,c,y,x] * in2[b,c,y+2*(iy-10),x+2*(ix-10)]
//
// Block = (b, 16-row y-tile, iy), all 21 ix. Parity-split in2 in LDS,
// double-buffered, ONE raw s_barrier per 1-channel chunk (lgkmcnt-only wait:
// in2 register prefetch stays in flight across the barrier, counted vmcnt).
// CK=1 keeps peak live regs ~248 (VGPR+AGPR unified) <= 256 -> no scratch
// (round-4 lesson: CK=2 spilled, 3.8 GB scratch writes). in1 via coalesced
// float4 + DPP lane^1 exchange. acc[8][21]; fmac accumulates into AGPRs.
// Final chunk peeled with prefetch disabled (no OOB read past in2).

#define CC 256
#define HH 96
#define WW 128
#define DD 21
#define TY 16
#define NCHUNK CC               // 256 single-channel chunks
#define HWi (HH * WW)           // 12288

#define S2 92                   // plane stride: 10 pad + 64 data + 18 pad
#define S2_TOT (TY * 2 * S2)    // 2944 floats = 11776 B per buffer

__device__ __forceinline__ float4 dppswap4(float4 x) {
    float4 y;
    y.x = __int_as_float(__builtin_amdgcn_mov_dpp(__float_as_int(x.x), 0xB1, 0xF, 0xF, true));
    y.y = __int_as_float(__builtin_amdgcn_mov_dpp(__float_as_int(x.y), 0xB1, 0xF, 0xF, true));
    y.z = __int_as_float(__builtin_amdgcn_mov_dpp(__float_as_int(x.z), 0xB1, 0xF, 0xF, true));
    y.w = __int_as_float(__builtin_amdgcn_mov_dpp(__float_as_int(x.w), 0xB1, 0xF, 0xF, true));
    return y;
}

// Barrier WITHOUT the vmcnt drain __syncthreads() emits: ds ops must be
// complete (lgkmcnt(0)); global loads may stay outstanding.
__device__ __forceinline__ void lds_barrier() {
    asm volatile("s_waitcnt lgkmcnt(0)" ::: "memory");
    __builtin_amdgcn_s_barrier();
}

__global__ __launch_bounds__(256, 2) void corr_kernel(const float* __restrict__ in1,
                                                      const float* __restrict__ in2,
                                                      float* __restrict__ out)
{
    __shared__ __align__(16) float s2[2][S2_TOT];

    // 1008 blocks = 8 XCDs * 126; all 21 iy of a (b,y-tile) on one XCD's L2
    // (each XCD ends up owning exactly one batch image's in2).
    const int bx = blockIdx.x;
    const int logical = (bx & 7) * 126 + (bx >> 3);
    const int iy = logical % DD;
    const int t  = logical / DD;
    const int y0 = (t % 6) * TY;
    const int b  = t / 6;

    // lane map: tid = r*16 + g*2 + p  (p = x-parity, g = 8-pixel group, r = row)
    const int tid = threadIdx.x;
    const int p = tid & 1;
    const int g = (tid >> 1) & 7;
    const int r = tid >> 4;
    const int u0 = g * 8;               // first half-position (8 per thread)

    const float* base1 = in1 + (size_t)b * CC * HWi;
    const float* base2 = in2 + (size_t)b * CC * HWi;

    // in2 staging map: 2 float4 loads/thread/chunk (16 rows x 32 float4 = 512)
    int l2a[2];
    bool ok2[2];
    const float* p2[2];
#pragma unroll
    for (int i = 0; i < 2; ++i) {
        const int v   = i * 256 + tid;
        const int row = v >> 5;             // 0..15
        const int xq  = v & 31;             // float4 column
        const int y2  = y0 + row + 2 * iy - 20;
        ok2[i] = ((unsigned)y2 < (unsigned)HH);
        p2[i] = base2 + (ok2[i] ? y2 : 0) * WW + xq * 4;
        l2a[i] = (row * 2) * S2 + 10 + xq * 2;   // even plane; odd = +S2
    }

    // in1: thread's 2 float4 cover x in [16g+8p, 16g+8p+8)
    const float* ap = base1 + (y0 + r) * WW + 16 * g + 8 * p;

    float acc[8][DD];
#pragma unroll
    for (int pi = 0; pi < 8; ++pi)
#pragma unroll
        for (int k = 0; k < DD; ++k) acc[pi][k] = 0.0f;

    // prologue: issue chunk-0 in2 loads, then zero both buffers
    float4 r2[2];
#pragma unroll
    for (int i = 0; i < 2; ++i) r2[i] = *(const float4*)(p2[i]);

    // pre-zero BOTH buffers: x-pads and OOB rows stay zero forever
    for (int i = tid; i < 2 * S2_TOT; i += 256) ((float*)s2)[i] = 0.0f;

    lds_barrier();   // zeroing visible; r2 prefetch still in flight

// PRE=1: prefetch next chunk's in2 into r2 (stays in flight across barrier).
// PRE=0 (final chunk): no prefetch -> no read past the end of in2.
#define CHUNK_BODY(BUF, PRE)                                                   \
    {                                                                          \
        float* sb = &s2[(BUF)][0];                                             \
        /* ds_write waits (counted vmcnt) only on this chunk's r2 */           \
        _Pragma("unroll")                                                      \
        for (int i = 0; i < 2; ++i) {                                          \
            if (ok2[i]) {                                                      \
                *(float2*)&sb[l2a[i]]      = make_float2(r2[i].x, r2[i].z);    \
                *(float2*)&sb[l2a[i] + S2] = make_float2(r2[i].y, r2[i].w);    \
            }                                                                  \
            p2[i] += HWi;                                                      \
        }                                                                      \
        /* in1 loads for this chunk (use waits counted vmcnt, not 0) */        \
        const float4 ma = *(const float4*)(ap);                                \
        const float4 mb = *(const float4*)(ap + 4);                            \
        ap += HWi;                                                             \
        if (PRE) {                                                             \
            _Pragma("unroll")                                                  \
            for (int i = 0; i < 2; ++i) r2[i] = *(const float4*)(p2[i]);       \
        }                                                                      \
        lds_barrier();                                                         \
        {                                                                      \
            const float* pl = &sb[(r * 2 + p) * S2 + u0];                      \
            float v[28];                                                       \
            _Pragma("unroll")                                                  \
            for (int j = 0; j < 7; ++j) {                                      \
                const float4 t4 = *(const float4*)(pl + 4 * j);                \
                v[4*j+0] = t4.x; v[4*j+1] = t4.y;                              \
                v[4*j+2] = t4.z; v[4*j+3] = t4.w;                              \
            }                                                                  \
            const float4 qa = dppswap4(ma);                                    \
            const float4 qb = dppswap4(mb);                                    \
            float a[8];                                                        \
            a[0] = p ? qa.y : ma.x;  a[1] = p ? qa.w : ma.z;                   \
            a[2] = p ? qb.y : mb.x;  a[3] = p ? qb.w : mb.z;                   \
            a[4] = p ? ma.y : qa.x;  a[5] = p ? ma.w : qa.z;                   \
            a[6] = p ? mb.y : qb.x;  a[7] = p ? mb.w : qb.z;                   \
            _Pragma("unroll")                                                  \
            for (int pi = 0; pi < 8; ++pi)                                     \
                _Pragma("unroll")                                              \
                for (int k = 0; k < DD; ++k)                                   \
                    acc[pi][k] = fmaf(a[pi], v[pi + k], acc[pi][k]);           \
        }                                                                      \
    }

#pragma unroll 1
    for (int mm = 0; mm < NCHUNK / 2 - 1; ++mm) {
        CHUNK_BODY(0, 1)
        CHUNK_BODY(1, 1)
    }
    CHUNK_BODY(0, 1)     // chunk 254 (prefetches chunk 255)
    CHUNK_BODY(1, 0)     // chunk 255 (no prefetch -> no OOB)
#undef CHUNK_BODY

    // epilogue: scale + store (thread covers x stride-2 over a 16-dword span;
    // partner parity lane covers the complement -> L2 write-combines)
    const float sc = 1.0f / (float)CC;
    const size_t hw = (size_t)HWi;
    size_t ob = ((size_t)b * (DD * DD) + (size_t)(iy * DD)) * hw
              + (size_t)(y0 + r) * WW + 16 * g + p;
#pragma unroll
    for (int k = 0; k < DD; ++k) {
#pragma unroll
        for (int pi = 0; pi < 8; ++pi)
            out[ob + 2 * pi] = acc[pi][k] * sc;
        ob += hw;
    }
}

extern "C" void kernel_launch(void* const* d_in, const int* in_sizes, int n_in,
                              void* d_out, int out_size, void* d_ws, size_t ws_size,
                              hipStream_t stream)
{
    const float* in1 = (const float*)d_in[0];
    const float* in2 = (const float*)d_in[1];
    float* out = (float*)d_out;
    (void)in_sizes; (void)n_in; (void)d_ws; (void)ws_size; (void)out_size;

    corr_kernel<<<dim3(8 * 6 * DD), dim3(256), 0, stream>>>(in1, in2, out);
}